// Round 9
// baseline (90.516 us; speedup 1.0000x reference)
//
#include <hip/hip_runtime.h>
#include <hip/hip_bf16.h>
#include <math.h>

#define CIN    1024
#define S_TOT  400
#define COUT   255
#define NCH    85
#define NIMG   64
#define SB     16            // spatial columns per GEMM block
#define NTHR   256

// GEMM LDS: X image for the block, g-major: granule (g 0..127, sp 0..15) at
// byte g*256 + sp*16  ->  32 KB, staged as a linear global_load_lds copy.
#define LDS_BYTES 32768

typedef __attribute__((ext_vector_type(8))) short bf16x8;
typedef __attribute__((ext_vector_type(4))) float f32x4;

// 16B store with 4B alignment guarantee (out row stride 85 floats)
struct __attribute__((aligned(4))) f4u { float x, y, z, w; };

__device__ __forceinline__ unsigned pk2(float a, float b) {
    __hip_bfloat162 h;
    h.x = __float2bfloat16(a);
    h.y = __float2bfloat16(b);
    return *reinterpret_cast<unsigned*>(&h);
}

__device__ __forceinline__ float sigmoidf_(float v) {
    return 1.0f / (1.0f + expf(-v));
}

__device__ __forceinline__ void gload_lds16(const void* g, void* l) {
    __builtin_amdgcn_global_load_lds(
        (const __attribute__((address_space(1))) unsigned int*)g,
        (__attribute__((address_space(3))) unsigned int*)l,
        16, 0, 0);
}

// ---- W pre-pack: fp32 -> bf16, granule-major [g][co][8k] (512 KiB) ----
__global__ __launch_bounds__(256) void w_pre2(const float* __restrict__ w,
                                              unsigned short* __restrict__ wbf) {
    int gidx = blockIdx.x * 256 + threadIdx.x;
    int co = gidx & 255;
    int g  = gidx >> 8;
    union { unsigned short u[8]; bf16x8 v; } pk;
    if (co < COUT) {
        const float* src = w + (size_t)co * CIN + g * 8;
        #pragma unroll
        for (int j = 0; j < 8; ++j) {
            __hip_bfloat16 h = __float2bfloat16(src[j]);
            pk.u[j] = *reinterpret_cast<unsigned short*>(&h);
        }
    } else {
        #pragma unroll
        for (int j = 0; j < 8; ++j) pk.u[j] = 0;
    }
    *reinterpret_cast<bf16x8*>((char*)wbf + ((size_t)(g << 8) + co) * 16) = pk.v;
}

// ---- X pre-pack: DENSE fp32 read, in-register transpose, bf16 granule write.
// Layout: granule (n, g, s) at ushort offset ((n*128 + g)*400 + s)*8.
// Block = (g-chunk of 4, n); wave w owns g = gc*4 + w (8 ci rows x 400 s).
// Lane l holds s-quads q = l and q = 64+l -> all 8 ci for its 4 s in regs.
__global__ __launch_bounds__(256) void x_pack(const float* __restrict__ xin,
                                              unsigned short* __restrict__ xp) {
    const int n    = blockIdx.y;
    const int wid  = threadIdx.x >> 6;
    const int lane = threadIdx.x & 63;
    const int g    = blockIdx.x * 4 + wid;

    const float* src = xin + ((size_t)n * CIN + g * 8) * S_TOT;
    union F4 { float4 v; float f[4]; };
    F4 v[8][2];

    #pragma unroll
    for (int ci = 0; ci < 8; ++ci) {
        v[ci][0].v = *(const float4*)(src + ci * S_TOT + lane * 4);
        if (lane < 36)
            v[ci][1].v = *(const float4*)(src + ci * S_TOT + (64 + lane) * 4);
    }

    unsigned short* dst = xp + ((size_t)(n * 128 + g) * S_TOT) * 8;
    #pragma unroll
    for (int r = 0; r < 2; ++r) {
        const int q = r * 64 + lane;
        if (r == 1 && lane >= 36) break;
        #pragma unroll
        for (int sj = 0; sj < 4; ++sj) {
            union { unsigned u4[4]; bf16x8 b; } rr;
            #pragma unroll
            for (int j = 0; j < 4; ++j)
                rr.u4[j] = pk2(v[2 * j][r].f[sj], v[2 * j + 1][r].f[sj]);
            *(bf16x8*)(dst + (size_t)(q * 4 + sj) * 8) = rr.b;
        }
    }
}

// ---- GEMM: block = 16 s x 1 img, all 255 co; X staged from packed buffer
//      via linear global_load_lds; A from L2-resident packed W ----
__global__ __launch_bounds__(NTHR, 4) void yolo_mfma5(
    const unsigned short* __restrict__ xp,
    const unsigned short* __restrict__ wbf,
    const float* __restrict__ bias,
    float* __restrict__ out)
{
    __shared__ __align__(16) char smem[LDS_BYTES];

    const int sb  = blockIdx.x * SB;
    const int n   = blockIdx.y;
    const int tid = threadIdx.x;
    const int lane = tid & 63;
    const int wid  = tid >> 6;
    const int llo  = lane & 15;
    const int lhi  = lane >> 4;

    // ---- stage X tile: 2048 granules; dest linear (i*4096 + wid*1024 + lane*16),
    //      per-lane src (g, sp) from the packed [n][g][s400] layout ----
    const char* xsrc = (const char*)xp + (size_t)n * 128 * S_TOT * 16;
    #pragma unroll
    for (int i = 0; i < 8; ++i) {
        const int d  = i * 256 + tid;       // dest granule = g*16 + sp
        const int g  = d >> 4;
        const int sp = d & 15;
        gload_lds16(xsrc + ((size_t)g * S_TOT + sb + sp) * 16,
                    smem + i * 4096 + wid * 1024);
    }
    __syncthreads();   // single barrier

    // ---- 32 barrier-free K-steps per wave, 1-deep prefetch ----
    f32x4 acc[4] = {};
    const char* wb = (const char*)wbf;
    const int coB = wid * 64 + llo;

    bf16x8 b_c = *(bf16x8*)(smem + lhi * 256 + llo * 16);
    bf16x8 a_c[4];
    #pragma unroll
    for (int mi = 0; mi < 4; ++mi)
        a_c[mi] = *(const bf16x8*)(wb + ((size_t)((lhi << 8) + coB + mi * 16)) * 16);

    #pragma unroll 4
    for (int kk = 0; kk < 31; ++kk) {
        const int gn = (kk + 1) * 4 + lhi;
        bf16x8 b_n = *(bf16x8*)(smem + gn * 256 + llo * 16);
        bf16x8 a_n[4];
        #pragma unroll
        for (int mi = 0; mi < 4; ++mi)
            a_n[mi] = *(const bf16x8*)(wb + ((size_t)((gn << 8) + coB + mi * 16)) * 16);
        #pragma unroll
        for (int mi = 0; mi < 4; ++mi)
            acc[mi] = __builtin_amdgcn_mfma_f32_16x16x32_bf16(a_c[mi], b_c, acc[mi], 0, 0, 0);
        b_c = b_n;
        #pragma unroll
        for (int mi = 0; mi < 4; ++mi) a_c[mi] = a_n[mi];
    }
    #pragma unroll
    for (int mi = 0; mi < 4; ++mi)
        acc[mi] = __builtin_amdgcn_mfma_f32_16x16x32_bf16(a_c[mi], b_c, acc[mi], 0, 0, 0);

    // ---- fused YOLO epilogue: 16B stores of 4 consecutive co ----
    const float anchW[3] = {116.0f, 156.0f, 373.0f};
    const float anchH[3] = {90.0f, 198.0f, 326.0f};

    const int s = sb + llo;
    const float sx = (float)(s % 20);
    const float sy = (float)(s / 20);

    #pragma unroll
    for (int mi = 0; mi < 4; ++mi) {
        const int co0 = wid * 64 + mi * 16 + lhi * 4;
        const int aW  = co0 / NCH;
        const int c0  = co0 - aW * NCH;
        const bool whole = (c0 <= NCH - 4) && (co0 + 3 < COUT);
        float bv[4];
        #pragma unroll
        for (int r = 0; r < 4; ++r)
            bv[r] = (co0 + r < COUT) ? bias[co0 + r] : 0.0f;

        if (whole) {
            float r4[4];
            #pragma unroll
            for (int r = 0; r < 4; ++r) {
                const int c = c0 + r;
                const float v = acc[mi][r] + bv[r];
                float res;
                if (c == 0)      res = (sigmoidf_(v) + sx) * 32.0f;
                else if (c == 1) res = (sigmoidf_(v) + sy) * 32.0f;
                else if (c == 2) res = expf(v) * anchW[aW];
                else if (c == 3) res = expf(v) * anchH[aW];
                else             res = sigmoidf_(v);
                r4[r] = res;
            }
            f4u* p = (f4u*)(out + (size_t)n * 102000 + aW * 34000 + s * 85 + c0);
            f4u val = {r4[0], r4[1], r4[2], r4[3]};
            *p = val;
        } else {
            #pragma unroll
            for (int r = 0; r < 4; ++r) {
                const int co = co0 + r;
                if (co < COUT) {
                    const int a2 = co / NCH;
                    const int c  = co - a2 * NCH;
                    const float v = acc[mi][r] + bv[r];
                    float res;
                    if (c == 0)      res = (sigmoidf_(v) + sx) * 32.0f;
                    else if (c == 1) res = (sigmoidf_(v) + sy) * 32.0f;
                    else if (c == 2) res = expf(v) * anchW[a2];
                    else if (c == 3) res = expf(v) * anchH[a2];
                    else             res = sigmoidf_(v);
                    out[(size_t)n * 102000 + a2 * 34000 + s * 85 + c] = res;
                }
            }
        }
    }
}

extern "C" void kernel_launch(void* const* d_in, const int* in_sizes, int n_in,
                              void* d_out, int out_size, void* d_ws, size_t ws_size,
                              hipStream_t stream) {
    const float* xin  = (const float*)d_in[0];
    const float* w    = (const float*)d_in[1];
    const float* bias = (const float*)d_in[2];
    float* out = (float*)d_out;
    unsigned short* wbf = (unsigned short*)d_ws;                    // 512 KiB
    unsigned short* xp  = (unsigned short*)((char*)d_ws + 524288);  // 52.4 MiB

    w_pre2<<<128, 256, 0, stream>>>(w, wbf);
    x_pack<<<dim3(32, NIMG), 256, 0, stream>>>(xin, xp);
    yolo_mfma5<<<dim3(S_TOT / SB, NIMG), NTHR, 0, stream>>>(xp, wbf, bias, out);
}

// Round 10
// 69.220 us; speedup vs baseline: 1.3077x; 1.3077x over previous
//
#include <hip/hip_runtime.h>
#include <hip/hip_bf16.h>
#include <math.h>

#define CIN    1024
#define S_TOT  400
#define COUT   255
#define NCH    85
#define NIMG   64
#define NFLAT  (NIMG * S_TOT)   // 25600 flat spatial positions
#define TS     64               // flat-s tile per block
#define NTHR   512
#define NPH    4                // K phases
#define KPH    256              // ci per phase
#define GPH    32               // k-granules (8 ci) per phase

// LDS: one X buffer = 64 s x 32 g x 16B = 32 KB; double-buffered
#define XBUF_B    32768
#define LDS_BYTES (2 * XBUF_B)

typedef __attribute__((ext_vector_type(8))) short bf16x8;
typedef __attribute__((ext_vector_type(4))) float f32x4;

// 16B store with 4B alignment guarantee (out row stride 85 floats)
struct __attribute__((aligned(4))) f4u { float x, y, z, w; };

// X LDS granule (s in [0,64), g in [0,32)): row = s (512B), XOR-swizzle mixes
// s low bits AND s>>3 so both 16-row column reads and 4s-strided writes spread.
__device__ __forceinline__ int xoff0(int s, int g) {
    return (s << 9) + ((g << 4) ^ (((s ^ (s >> 3)) & 7) << 4));
}

__device__ __forceinline__ unsigned pk2(float a, float b) {
    __hip_bfloat162 h;
    h.x = __float2bfloat16(a);
    h.y = __float2bfloat16(b);
    return *reinterpret_cast<unsigned*>(&h);
}

__device__ __forceinline__ float sigmoidf_(float v) {
    return 1.0f / (1.0f + expf(-v));
}

// ---- W pre-pack: fp32 -> bf16, granule-major [gg][co][8k] (512 KiB) ----
__global__ __launch_bounds__(256) void w_pre2(const float* __restrict__ w,
                                              unsigned short* __restrict__ wbf) {
    int gidx = blockIdx.x * 256 + threadIdx.x;
    int co = gidx & 255;
    int gg = gidx >> 8;
    union { unsigned short u[8]; bf16x8 v; } pk;
    if (co < COUT) {
        const float* src = w + (size_t)co * CIN + gg * 8;
        #pragma unroll
        for (int j = 0; j < 8; ++j) {
            __hip_bfloat16 h = __float2bfloat16(src[j]);
            pk.u[j] = *reinterpret_cast<unsigned short*>(&h);
        }
    } else {
        #pragma unroll
        for (int j = 0; j < 8; ++j) pk.u[j] = 0;   // pad co=255
    }
    *reinterpret_cast<bf16x8*>((char*)wbf + ((size_t)(gg << 8) + co) * 16) = pk.v;
}

// ---- main: weight-stream GEMM, dense fused X transpose, 4 K-phases ----
__global__ __launch_bounds__(NTHR, 4) void yolo_ws(
    const float* __restrict__ xin,
    const unsigned short* __restrict__ wbf,
    const float* __restrict__ bias,
    float* __restrict__ out)
{
    __shared__ __align__(16) char smem[LDS_BYTES];

    const int tile = blockIdx.x * TS;
    const int tid  = threadIdx.x;
    const int lane = tid & 63;
    const int w    = tid >> 6;       // wave 0..7, owns co [32w, 32w+32)
    const int llo  = lane & 15;
    const int lhi  = lane >> 4;

    // staging lane geometry: quarter-wave lanes (llo) sweep 16 consecutive
    // float4 -> 256B dense chunk per ci row; lhi picks one of 4 ci-octets.
    const int flat_l = tile + 4 * llo;           // 4-aligned, never straddles an image
    const int n_l = flat_l / S_TOT;
    const int s_l = flat_l - n_l * S_TOT;
    const float* xbase = xin + (size_t)n_l * (CIN * S_TOT) + s_l;
    const int ci_row = w * 32 + lhi * 8;         // within-phase ci base (32 ci/wave)
    const int g_loc  = w * 4 + lhi;              // LDS granule column

    f32x4 acc[2][4] = {};
    union F4 { float4 v; float f[4]; };
    F4 st[8];

    // ---- prologue: stage phase 0 into buf 0 ----
    {
        const float* src = xbase + (size_t)ci_row * S_TOT;
        #pragma unroll
        for (int j = 0; j < 8; ++j) st[j].v = *(const float4*)(src + j * S_TOT);
        #pragma unroll
        for (int r = 0; r < 4; ++r) {
            union { unsigned u4[4]; bf16x8 b; } rr;
            #pragma unroll
            for (int jj = 0; jj < 4; ++jj)
                rr.u4[jj] = pk2(st[2 * jj].f[r], st[2 * jj + 1].f[r]);
            *(bf16x8*)(smem + xoff0(4 * llo + r, g_loc)) = rr.b;
        }
    }

    for (int p = 0; p < NPH; ++p) {
        // issue next phase's dense loads EARLY (regs); no vmcnt drain at barrier
        if (p + 1 < NPH) {
            const float* src = xbase + (size_t)((p + 1) * KPH + ci_row) * S_TOT;
            #pragma unroll
            for (int j = 0; j < 8; ++j) st[j].v = *(const float4*)(src + j * S_TOT);
        }
        __builtin_amdgcn_sched_barrier(0);
        // own ds_writes visible, then barrier; vmcnt deliberately NOT drained
        asm volatile("s_waitcnt lgkmcnt(0)" ::: "memory");
        __builtin_amdgcn_s_barrier();
        __builtin_amdgcn_sched_barrier(0);

        // ---- compute phase p from buf p&1: 8 k-steps, 8 MFMAs each ----
        const char* xb = smem + (p & 1) * XBUF_B;
        #pragma unroll
        for (int step = 0; step < 8; ++step) {
            const int gl = step * 4 + lhi;
            bf16x8 bfr[4];
            #pragma unroll
            for (int ns = 0; ns < 4; ++ns)
                bfr[ns] = *(const bf16x8*)(xb + xoff0(ns * 16 + llo, gl));
            #pragma unroll
            for (int mi = 0; mi < 2; ++mi) {
                const int co = w * 32 + mi * 16 + llo;
                bf16x8 a = *(const bf16x8*)((const char*)wbf
                            + ((size_t)(((p * GPH + gl) << 8) + co)) * 16);
                #pragma unroll
                for (int ns = 0; ns < 4; ++ns)
                    acc[mi][ns] = __builtin_amdgcn_mfma_f32_16x16x32_bf16(
                        a, bfr[ns], acc[mi][ns], 0, 0, 0);
            }
        }

        // ---- pack + write next phase into the other buffer (after compute;
        //      safe: all waves are past this phase's barrier) ----
        if (p + 1 < NPH) {
            char* xb2 = smem + ((p + 1) & 1) * XBUF_B;
            #pragma unroll
            for (int r = 0; r < 4; ++r) {
                union { unsigned u4[4]; bf16x8 b; } rr;
                #pragma unroll
                for (int jj = 0; jj < 4; ++jj)
                    rr.u4[jj] = pk2(st[2 * jj].f[r], st[2 * jj + 1].f[r]);
                *(bf16x8*)(xb2 + xoff0(4 * llo + r, g_loc)) = rr.b;
            }
        }
    }

    // ---- fused YOLO epilogue: 16B stores of 4 consecutive co ----
    const float anchW[3] = {116.0f, 156.0f, 373.0f};
    const float anchH[3] = {90.0f, 198.0f, 326.0f};

    #pragma unroll
    for (int mi = 0; mi < 2; ++mi) {
        const int co0 = w * 32 + mi * 16 + lhi * 4;
        const int aW  = co0 / NCH;
        const int c0  = co0 - aW * NCH;
        const bool whole = (c0 <= NCH - 4) && (co0 + 3 < COUT);
        float bv[4];
        #pragma unroll
        for (int r = 0; r < 4; ++r)
            bv[r] = (co0 + r < COUT) ? bias[co0 + r] : 0.0f;

        #pragma unroll
        for (int ns = 0; ns < 4; ++ns) {
            const int flat = tile + ns * 16 + llo;
            const int n = flat / S_TOT;
            const int s = flat - n * S_TOT;
            const float sx = (float)(s % 20);
            const float sy = (float)(s / 20);
            if (whole) {
                float r4[4];
                #pragma unroll
                for (int r = 0; r < 4; ++r) {
                    const int c = c0 + r;
                    const float v = acc[mi][ns][r] + bv[r];
                    float res;
                    if (c == 0)      res = (sigmoidf_(v) + sx) * 32.0f;
                    else if (c == 1) res = (sigmoidf_(v) + sy) * 32.0f;
                    else if (c == 2) res = expf(v) * anchW[aW];
                    else if (c == 3) res = expf(v) * anchH[aW];
                    else             res = sigmoidf_(v);
                    r4[r] = res;
                }
                f4u* pp = (f4u*)(out + (size_t)n * 102000 + aW * 34000 + s * 85 + c0);
                f4u val = {r4[0], r4[1], r4[2], r4[3]};
                *pp = val;
            } else {
                #pragma unroll
                for (int r = 0; r < 4; ++r) {
                    const int co = co0 + r;
                    if (co < COUT) {
                        const int a2 = co / NCH;
                        const int c  = co - a2 * NCH;
                        const float v = acc[mi][ns][r] + bv[r];
                        float res;
                        if (c == 0)      res = (sigmoidf_(v) + sx) * 32.0f;
                        else if (c == 1) res = (sigmoidf_(v) + sy) * 32.0f;
                        else if (c == 2) res = expf(v) * anchW[a2];
                        else if (c == 3) res = expf(v) * anchH[a2];
                        else             res = sigmoidf_(v);
                        out[(size_t)n * 102000 + a2 * 34000 + s * 85 + c] = res;
                    }
                }
            }
        }
    }
}

extern "C" void kernel_launch(void* const* d_in, const int* in_sizes, int n_in,
                              void* d_out, int out_size, void* d_ws, size_t ws_size,
                              hipStream_t stream) {
    const float* xin  = (const float*)d_in[0];
    const float* w    = (const float*)d_in[1];
    const float* bias = (const float*)d_in[2];
    float* out = (float*)d_out;
    unsigned short* wbf = (unsigned short*)d_ws;   // 512 KiB granule-major W

    w_pre2<<<128, 256, 0, stream>>>(w, wbf);
    yolo_ws<<<NFLAT / TS, NTHR, 0, stream>>>(xin, wbf, bias, out);
}